// Round 19
// baseline (291.077 us; speedup 1.0000x reference)
//
#include <hip/hip_runtime.h>
#include <hip/hip_bf16.h>
#include <stdint.h>

#define SEQ 4096
#define DM 2048
#define NH 16
#define HD 128

typedef __attribute__((ext_vector_type(4)))  float f32x4;
typedef __attribute__((ext_vector_type(16))) float f32x16;
typedef __attribute__((ext_vector_type(8)))  short bf16x8;
typedef __attribute__((ext_vector_type(4)))  float float4_t;
typedef __attribute__((ext_vector_type(4)))  short s16x4;
typedef __attribute__((ext_vector_type(2)))  int   i32x2;
typedef __attribute__((ext_vector_type(2)))  unsigned u32x2;

__device__ __forceinline__ short f2bf(float f) {
  union { float f; unsigned u; } c; c.f = f;
  unsigned u = c.u;
  u += 0x7FFFu + ((u >> 16) & 1u);   // RNE
  return (short)(u >> 16);
}
__device__ __forceinline__ float bf2f(short s) {
  union { unsigned u; float f; } c;
  c.u = ((unsigned)(unsigned short)s) << 16;
  return c.f;
}

__device__ __forceinline__ int cvtpk(float lo, float hi) {
  int r;
  asm("v_cvt_pk_bf16_f32 %0, %1, %2" : "=v"(r) : "v"(lo), "v"(hi));
  return r;
}

__device__ __forceinline__ float exp2r(float x) {   // raw v_exp_f32
  return __builtin_amdgcn_exp2f(x);
}

__device__ __forceinline__ void async16(const void* g, void* l) {
  __builtin_amdgcn_global_load_lds((const __attribute__((address_space(1))) void*)g,
                                   (__attribute__((address_space(3))) void*)l, 16, 0, 0);
}

__global__ __launch_bounds__(256) void rope_tables_kernel(float2* __restrict__ tab) {
  int idx = blockIdx.x * 256 + threadIdx.x;  // SEQ*64
  int s = idx >> 6, j = idx & 63;
  float invf = expf(-(float)j * (9.210340371976184f / 64.0f)); // 10000^(-j/64)
  float ang = (float)s * invf;
  tab[idx] = make_float2(cosf(ang), sinf(ang));
}

__global__ __launch_bounds__(256) void f32_to_bf16_kernel(const float* __restrict__ in,
                                                          short* __restrict__ out, int n4) {
  int stride = gridDim.x * 256;
  for (int i = blockIdx.x * 256 + threadIdx.x; i < n4; i += stride) {
    float4_t v = ((const float4_t*)in)[i];
    s16x4 r;
    #pragma unroll
    for (int u = 0; u < 4; u++) r[u] = f2bf(v[u]);
    ((s16x4*)out)[i] = r;
  }
}

// Convert 3 weights (wq,wk,wv) into one contiguous bf16 buffer in one launch.
__global__ __launch_bounds__(256) void w3_to_bf16_kernel(
    const float* __restrict__ wq, const float* __restrict__ wk,
    const float* __restrict__ wv, short* __restrict__ out) {
  const int n4w = DM * DM / 4;              // 2^20 per weight
  int stride = gridDim.x * 256;
  for (int i = blockIdx.x * 256 + threadIdx.x; i < 3 * n4w; i += stride) {
    int j = i >> 20;                        // weight index
    int loc = i & (n4w - 1);
    const float* src = (j == 0) ? wq : (j == 1) ? wk : wv;
    float4_t v = ((const float4_t*)src)[loc];
    s16x4 r;
    #pragma unroll
    for (int u = 0; u < 4; u++) r[u] = f2bf(v[u]);
    ((s16x4*)out)[i] = r;
  }
}

// RoPE in-place on Q (scale log2e/sqrt(HD), exp2 domain) and K (scale 1).
__global__ __launch_bounds__(256) void rope_apply_kernel(
    short* __restrict__ Q, short* __restrict__ K, const float2* __restrict__ tab) {
  int idx = blockIdx.x * 256 + threadIdx.x;   // SEQ*NH*16
  int j4 = (idx & 15) * 4;
  int h  = (idx >> 4) & 15;
  int s  = idx >> 8;
  const float SCQ = 0.12751746f;
  size_t base = (size_t)s * DM + h * HD;
  s16x4 q1 = *(s16x4*)(Q + base + j4),      q2 = *(s16x4*)(Q + base + 64 + j4);
  s16x4 k1 = *(s16x4*)(K + base + j4),      k2 = *(s16x4*)(K + base + 64 + j4);
  s16x4 o1, o2, p1, p2;
  #pragma unroll
  for (int u = 0; u < 4; u++) {
    float2 cs = tab[s * 64 + j4 + u];
    float c = cs.x, sn = cs.y;
    float a = bf2f(q1[u]), b = bf2f(q2[u]);
    o1[u] = f2bf((a * c - b * sn) * SCQ);
    o2[u] = f2bf((b * c + a * sn) * SCQ);
    a = bf2f(k1[u]); b = bf2f(k2[u]);
    p1[u] = f2bf(a * c - b * sn);
    p2[u] = f2bf(b * c + a * sn);
  }
  *(s16x4*)(Q + base + j4) = o1;  *(s16x4*)(Q + base + 64 + j4) = o2;
  *(s16x4*)(K + base + j4) = p1;  *(s16x4*)(K + base + 64 + j4) = p2;
}

// ---------------- 12-wave fused QKV GEMM: BM=256 BN=192 BK=32 --------------
// 768 thr = 12 waves 4Mx3N (64x64 per wave). B = [6144][2048] concat weights;
// per-n-frag region (16-aligned, never straddles 2048) selects Q/K/VT output.
// 3-deep LDS 84KB; A/B packed 2 rows per 128B ldsrow with XOR (ldsrow&7)<<4
// (proven 2-way-free in flash); 1 barrier/K-step; counted per-wave-class
// vmcnt (A-waves 2 ops/tile, B-waves 3). More waves/CU (12 vs 8) to overlap
// the LDS-read / MFMA / staging pipes that phase-lock at 2 waves/SIMD.
__global__ __launch_bounds__(768) void gemm_qkv12_kernel(
    const short* __restrict__ A, const short* __restrict__ B,
    short* __restrict__ Qout, short* __restrict__ Kout, short* __restrict__ VTout) {
  constexpr int K = DM, MM = SEQ;
  // buf b at b*28672: A 16KB (128 ldsrows x 128B), B 12KB (96 ldsrows).
  __shared__ __align__(16) char LB[86016];
  const int t = threadIdx.x, lane = t & 63, w = t >> 6;   // w: 0..11
  const int wm = w & 3, wn = w >> 2;                      // 4M x 3N
  const size_t Mbase = (size_t)blockIdx.x * 256;
  const size_t Bbase = (size_t)blockIdx.y * 192;
  const int nt = K / 32;                                  // 64

  auto stage = [&](int kt) {
    const int buf = kt % 3, k0 = kt * 32;
    if (w < 8) {            // A: wave w covers [w*2048, +2048)
      #pragma unroll
      for (int it = 0; it < 2; it++) {
        const int ob = w * 2048 + it * 1024;
        const int o = ob + lane * 16;
        const int lr = o >> 7;
        const int xs = (o & 127) ^ ((lr & 7) << 4);
        const int r = 2 * lr + (xs >> 6);
        async16((const char*)A + ((Mbase + r) * (size_t)K + k0) * 2 + (xs & 63),
                LB + buf * 28672 + ob);
      }
    } else {                // B: wave w-8 covers [(w-8)*3072, +3072)
      #pragma unroll
      for (int it = 0; it < 3; it++) {
        const int ob = (w - 8) * 3072 + it * 1024;
        const int o = ob + lane * 16;
        const int lr = o >> 7;
        const int xs = (o & 127) ^ ((lr & 7) << 4);
        const int r = 2 * lr + (xs >> 6);
        async16((const char*)B + ((Bbase + r) * (size_t)K + k0) * 2 + (xs & 63),
                LB + buf * 28672 + 16384 + ob);
      }
    }
  };

  f32x4 acc[4][4] = {};

  stage(0); stage(1);
  if (w < 8) asm volatile("s_waitcnt vmcnt(2)" ::: "memory");  // tile 0 landed
  else       asm volatile("s_waitcnt vmcnt(3)" ::: "memory");
  __builtin_amdgcn_s_barrier();

  for (int kt = 0; kt < nt; kt++) {
    const char* bufA = LB + (kt % 3) * 28672;
    const char* bufB = bufA + 16384;
    const bool pre = (kt + 2 < nt);
    bf16x8 a[4], b[4];

    const int cb = (lane >> 4) * 16;
    #pragma unroll
    for (int m = 0; m < 4; m++) {
      int r = wm * 64 + m * 16 + (lane & 15);
      a[m] = *(const bf16x8*)(bufA + (r >> 1) * 128
               + ((((r & 1) * 64) + cb) ^ (((r >> 1) & 7) << 4)));
    }
    #pragma unroll
    for (int n = 0; n < 4; n++) {
      int r = wn * 64 + n * 16 + (lane & 15);
      b[n] = *(const bf16x8*)(bufB + (r >> 1) * 128
               + ((((r & 1) * 64) + cb) ^ (((r >> 1) & 7) << 4)));
    }
    if (pre) stage(kt + 2);

    __builtin_amdgcn_s_setprio(1);
    #pragma unroll
    for (int m = 0; m < 4; m++)
      #pragma unroll
      for (int n = 0; n < 4; n++)
        acc[m][n] = __builtin_amdgcn_mfma_f32_16x16x32_bf16(
            a[m], b[n], acc[m][n], 0, 0, 0);
    __builtin_amdgcn_s_setprio(0);

    if (kt + 1 < nt) {
      if (pre) {
        if (w < 8) asm volatile("s_waitcnt vmcnt(2) lgkmcnt(0)" ::: "memory");
        else       asm volatile("s_waitcnt vmcnt(3) lgkmcnt(0)" ::: "memory");
      } else {
        asm volatile("s_waitcnt vmcnt(0) lgkmcnt(0)" ::: "memory");
      }
      __builtin_amdgcn_sched_barrier(0);
      __builtin_amdgcn_s_barrier();
    }
  }

  #pragma unroll
  for (int m = 0; m < 4; m++)
    #pragma unroll
    for (int n = 0; n < 4; n++) {
      const int brow0 = (int)Bbase + wn * 64 + n * 16;    // 16-aligned
      const int reg = brow0 >> 11;                        // uniform per frag
      #pragma unroll
      for (int j = 0; j < 4; j++) {
        size_t srow = Mbase + wm * 64 + m * 16 + (lane >> 4) * 4 + j;
        int col = (brow0 + (lane & 15)) & 2047;
        short v = f2bf(acc[m][n][j]);
        if (reg == 0)      Qout[srow * DM + col] = v;
        else if (reg == 1) Kout[srow * DM + col] = v;
        else               VTout[(size_t)col * MM + srow] = v;
      }
    }
}

// ---------------- fallback QKV GEMM (r17, regions + fused RoPE) ------------
__global__ __launch_bounds__(512) void gemm_qkv_kernel(
    const short* __restrict__ A, const short* __restrict__ B,
    short* __restrict__ Qout, short* __restrict__ Kout, short* __restrict__ VTout,
    const float2* __restrict__ tab, int region) {
  constexpr int NN = DM, K = DM, MM = SEQ;
  __shared__ __align__(16) char LB[147456];
  const int t = threadIdx.x, lane = t & 63, w = t >> 6;
  const int wm = w >> 1, wn = w & 1;
  const size_t Mbase = (size_t)blockIdx.x * 256;
  const int ry  = region;
  const size_t Bbase = (size_t)blockIdx.y * 128;
  const size_t Nbase = (size_t)blockIdx.y * 128;
  const int nt = K / 64;

  auto stageA = [&](int kt, int half) {
    const int buf = kt % 3, k0 = kt * 64;
    #pragma unroll
    for (int it = 0; it < 2; it++) {
      const int ob = half * 16384 + it * 8192 + w * 1024;
      const int o = ob + lane * 16;
      const int row = o >> 7;
      const int col = (o & 127) ^ ((row & 7) << 4);
      async16((const char*)A + ((Mbase + row) * (size_t)K + k0) * 2 + col,
              LB + buf * 32768 + ob);
    }
  };
  auto stageB = [&](int kt) {
    const int buf = kt % 3, k0 = kt * 64;
    #pragma unroll
    for (int it = 0; it < 2; it++) {
      const int ob = it * 8192 + w * 1024;
      const int o = ob + lane * 16;
      const int row = o >> 7;
      const int col = (o & 127) ^ ((row & 7) << 4);
      async16((const char*)B + ((Bbase + row) * (size_t)K + k0) * 2 + col,
              LB + 98304 + buf * 16384 + ob);
    }
  };

  f32x4 acc[4][4] = {};

  stageA(0, 0); stageA(0, 1); stageB(0);
  stageA(1, 0); stageA(1, 1); stageB(1);
  asm volatile("s_waitcnt vmcnt(6)" ::: "memory");
  __builtin_amdgcn_s_barrier();

  for (int kt = 0; kt < nt; kt++) {
    const char* AsB = LB + (kt % 3) * 32768;
    const char* BsB = LB + 98304 + (kt % 3) * 16384;
    const bool pre = (kt + 2 < nt);
    bf16x8 a[2][4], b[2][2], b2[2][2];

    #pragma unroll
    for (int ks = 0; ks < 2; ks++)
      #pragma unroll
      for (int m = 0; m < 4; m++) {
        int row = wm * 64 + m * 16 + (lane & 15);
        a[ks][m] = *(const bf16x8*)(AsB + row * 128
                    + ((ks * 64 + (lane >> 4) * 16) ^ ((row & 7) << 4)));
      }
    #pragma unroll
    for (int ks = 0; ks < 2; ks++)
      #pragma unroll
      for (int n = 0; n < 2; n++) {
        int row = n * 32 + wn * 16 + (lane & 15);
        b[ks][n] = *(const bf16x8*)(BsB + row * 128
                    + ((ks * 64 + (lane >> 4) * 16) ^ ((row & 7) << 4)));
      }
    if (pre) { stageA(kt + 2, 0); stageA(kt + 2, 1); stageB(kt + 2); }

    __builtin_amdgcn_s_setprio(1);
    #pragma unroll
    for (int ks = 0; ks < 2; ks++)
      #pragma unroll
      for (int m = 0; m < 4; m++)
        #pragma unroll
        for (int n = 0; n < 2; n++)
          acc[m][n] = __builtin_amdgcn_mfma_f32_16x16x32_bf16(
              a[ks][m], b[ks][n], acc[m][n], 0, 0, 0);
    __builtin_amdgcn_s_setprio(0);

    #pragma unroll
    for (int ks = 0; ks < 2; ks++)
      #pragma unroll
      for (int n = 0; n < 2; n++) {
        int row = (n + 2) * 32 + wn * 16 + (lane & 15);
        b2[ks][n] = *(const bf16x8*)(BsB + row * 128
                     + ((ks * 64 + (lane >> 4) * 16) ^ ((row & 7) << 4)));
      }
    __builtin_amdgcn_s_setprio(1);
    #pragma unroll
    for (int ks = 0; ks < 2; ks++)
      #pragma unroll
      for (int m = 0; m < 4; m++)
        #pragma unroll
        for (int n = 0; n < 2; n++)
          acc[m][n + 2] = __builtin_amdgcn_mfma_f32_16x16x32_bf16(
              a[ks][m], b2[ks][n], acc[m][n + 2], 0, 0, 0);
    __builtin_amdgcn_s_setprio(0);

    if (kt + 1 < nt) {
      if (pre) asm volatile("s_waitcnt vmcnt(6) lgkmcnt(0)" ::: "memory");
      else     asm volatile("s_waitcnt vmcnt(0) lgkmcnt(0)" ::: "memory");
      __builtin_amdgcn_sched_barrier(0);
      __builtin_amdgcn_s_barrier();
    }
  }

  if (ry < 2) {
    const float SC = (ry == 0) ? 0.12751746f : 1.0f;
    short* C = (ry == 0) ? Qout : Kout;
    #pragma unroll
    for (int m = 0; m < 4; m++)
      #pragma unroll
      for (int n = 0; n < 2; n++)
        #pragma unroll
        for (int j = 0; j < 4; j++) {
          int row = (int)Mbase + wm * 64 + m * 16 + (lane >> 4) * 4 + j;
          int dj = n * 32 + wn * 16 + (lane & 15);
          float2 cs = tab[row * 64 + dj];
          float cc = cs.x * SC, ss = cs.y * SC;
          float r1 = acc[m][n][j], r2 = acc[m][n + 2][j];
          C[(size_t)row * NN + Nbase + dj]      = f2bf(r1 * cc - r2 * ss);
          C[(size_t)row * NN + Nbase + dj + 64] = f2bf(r2 * cc + r1 * ss);
        }
  } else {
    #pragma unroll
    for (int m = 0; m < 4; m++)
      #pragma unroll
      for (int n = 0; n < 4; n++)
        #pragma unroll
        for (int j = 0; j < 4; j++) {
          size_t row = Mbase + wm * 64 + m * 16 + (lane >> 4) * 4 + j;
          size_t col = Nbase + n * 32 + wn * 16 + (lane & 15);
          VTout[col * (size_t)MM + row] = f2bf(acc[m][n][j]);
        }
  }
}

// ---------------- out-projection GEMM (r17 exact, f32 C) -------------------
__global__ __launch_bounds__(512) void gemm_out_kernel(
    const short* __restrict__ A, const short* __restrict__ B,
    float* __restrict__ Cp) {
  constexpr int NN = DM, K = DM;
  __shared__ __align__(16) char LB[147456];
  const int t = threadIdx.x, lane = t & 63, w = t >> 6;
  const int wm = w >> 1, wn = w & 1;
  const size_t Mbase = (size_t)blockIdx.x * 256;
  const size_t Nbase = (size_t)blockIdx.y * 128;
  const int nt = K / 64;

  auto stageA = [&](int kt, int half) {
    const int buf = kt % 3, k0 = kt * 64;
    #pragma unroll
    for (int it = 0; it < 2; it++) {
      const int ob = half * 16384 + it * 8192 + w * 1024;
      const int o = ob + lane * 16;
      const int row = o >> 7;
      const int col = (o & 127) ^ ((row & 7) << 4);
      async16((const char*)A + ((Mbase + row) * (size_t)K + k0) * 2 + col,
              LB + buf * 32768 + ob);
    }
  };
  auto stageB = [&](int kt) {
    const int buf = kt % 3, k0 = kt * 64;
    #pragma unroll
    for (int it = 0; it < 2; it++) {
      const int ob = it * 8192 + w * 1024;
      const int o = ob + lane * 16;
      const int row = o >> 7;
      const int col = (o & 127) ^ ((row & 7) << 4);
      async16((const char*)B + ((Nbase + row) * (size_t)K + k0) * 2 + col,
              LB + 98304 + buf * 16384 + ob);
    }
  };

  f32x4 acc[4][4] = {};

  stageA(0, 0); stageA(0, 1); stageB(0);
  stageA(1, 0); stageA(1, 1); stageB(1);
  asm volatile("s_waitcnt vmcnt(6)" ::: "memory");
  __builtin_amdgcn_s_barrier();

  for (int kt = 0; kt < nt; kt++) {
    const char* AsB = LB + (kt % 3) * 32768;
    const char* BsB = LB + 98304 + (kt % 3) * 16384;
    const bool pre = (kt + 2 < nt);
    bf16x8 a[2][4], b[2][2], b2[2][2];

    #pragma unroll
    for (int ks = 0; ks < 2; ks++)
      #pragma unroll
      for (int m = 0; m < 4; m++) {
        int row = wm * 64 + m * 16 + (lane & 15);
        a[ks][m] = *(const bf16x8*)(AsB + row * 128
                    + ((ks * 64 + (lane >> 4) * 16) ^ ((row & 7) << 4)));
      }
    #pragma unroll
    for (int ks = 0; ks < 2; ks++)
      #pragma unroll
      for (int n = 0; n < 2; n++) {
        int row = n * 32 + wn * 16 + (lane & 15);
        b[ks][n] = *(const bf16x8*)(BsB + row * 128
                    + ((ks * 64 + (lane >> 4) * 16) ^ ((row & 7) << 4)));
      }
    if (pre) { stageA(kt + 2, 0); stageA(kt + 2, 1); stageB(kt + 2); }

    __builtin_amdgcn_s_setprio(1);
    #pragma unroll
    for (int ks = 0; ks < 2; ks++)
      #pragma unroll
      for (int m = 0; m < 4; m++)
        #pragma unroll
        for (int n = 0; n < 2; n++)
          acc[m][n] = __builtin_amdgcn_mfma_f32_16x16x32_bf16(
              a[ks][m], b[ks][n], acc[m][n], 0, 0, 0);
    __builtin_amdgcn_s_setprio(0);

    #pragma unroll
    for (int ks = 0; ks < 2; ks++)
      #pragma unroll
      for (int n = 0; n < 2; n++) {
        int row = (n + 2) * 32 + wn * 16 + (lane & 15);
        b2[ks][n] = *(const bf16x8*)(BsB + row * 128
                     + ((ks * 64 + (lane >> 4) * 16) ^ ((row & 7) << 4)));
      }
    __builtin_amdgcn_s_setprio(1);
    #pragma unroll
    for (int ks = 0; ks < 2; ks++)
      #pragma unroll
      for (int m = 0; m < 4; m++)
        #pragma unroll
        for (int n = 0; n < 2; n++)
          acc[m][n + 2] = __builtin_amdgcn_mfma_f32_16x16x32_bf16(
              a[ks][m], b2[ks][n], acc[m][n + 2], 0, 0, 0);
    __builtin_amdgcn_s_setprio(0);

    if (kt + 1 < nt) {
      if (pre) asm volatile("s_waitcnt vmcnt(6) lgkmcnt(0)" ::: "memory");
      else     asm volatile("s_waitcnt vmcnt(0) lgkmcnt(0)" ::: "memory");
      __builtin_amdgcn_sched_barrier(0);
      __builtin_amdgcn_s_barrier();
    }
  }

  #pragma unroll
  for (int m = 0; m < 4; m++)
    #pragma unroll
    for (int n = 0; n < 4; n++)
      #pragma unroll
      for (int j = 0; j < 4; j++) {
        size_t row = Mbase + wm * 64 + m * 16 + (lane >> 4) * 4 + j;
        size_t col = Nbase + n * 32 + wn * 16 + (lane & 15);
        Cp[row * NN + col] = acc[m][n][j];
      }
}

// ---------------- flash attention (r17 exact: 107-108 us) ------------------
__global__ __launch_bounds__(512) void flash_attn9_kernel(
    const short* __restrict__ Q, const short* __restrict__ K,
    const short* __restrict__ VT, short* __restrict__ O) {
  __shared__ __align__(16) char LB[65536];
  const int t = threadIdx.x, lane = t & 63, w = t >> 6;   // w: 0..7
  const int hi = lane >> 5, c31 = lane & 31;
  const int s = w & 3, v = w >> 2;                // strip, kv-half
  const int id = blockIdx.x;                      // 0..511
  const int h  = (id & 7) * 2 + ((id >> 3) & 1);  // 2 heads per XCD
  const int pr = (id >> 4) & 15;                  // 0..15
  const int qt = (id < 256) ? pr : (31 - pr);     // 128-row q-tile

  auto stage = [&](int kt, int buf) {
    #pragma unroll
    for (int it = 0; it < 2; it++) {
      const int ob = it * 8192 + w * 1024;        // wave-uniform LDS byte base
      const int o  = ob + lane * 16;
      const int row = o >> 8;                     // 0..63
      const int xs = (o & 255) ^ ((row & 15) << 4);
      { const size_t src = ((size_t)(kt * 64 + row) * DM + h * HD) * 2 + xs;
        async16((const char*)K + src, LB + buf * 16384 + ob); }
      { const int d = 2 * row + (xs >> 7);
        const size_t src = ((size_t)(h * HD + d) * SEQ + (size_t)kt * 64) * 2
                         + (size_t)(xs & 127);
        async16((const char*)VT + src, LB + 32768 + buf * 16384 + ob); }
    }
  };

  const int q0 = qt * 128;
  const int nt = 2 * (qt + 1);                    // 64-key tiles
  const int qrow = q0 + s * 32 + c31;             // this lane's q-row

  stage(0, 0);

  bf16x8 qf[8];
  #pragma unroll
  for (int ss = 0; ss < 8; ss++)
    qf[ss] = *(const bf16x8*)(Q + (size_t)qrow * DM + h * HD + ss * 16 + hi * 8);

  f32x16 oacc[4] = {};
  float m = -3.0e38f, l = 0.f;

  __syncthreads();                                // stage(0) landed

  for (int kt = 0; kt < nt; kt++) {
    const int buf = kt & 1;
    if (kt + 1 < nt) stage(kt + 1, buf ^ 1);

    if (kt * 64 + v * 32 <= q0 + s * 32 + 31) {   // wave has unmasked work
      const char* KsB = LB + buf * 16384;
      const char* VsB = LB + 32768 + buf * 16384;

      f32x16 sacc = {};
      __builtin_amdgcn_s_setprio(1);
      #pragma unroll
      for (int ss = 0; ss < 8; ss++) {
        int row = v * 32 + c31;
        bf16x8 kf = *(const bf16x8*)(KsB + row * 256
                                     + ((ss * 32 + hi * 16) ^ ((row & 15) << 4)));
        sacc = __builtin_amdgcn_mfma_f32_32x32x16_bf16(kf, qf[ss], sacc, 0, 0, 0);
      }
      __builtin_amdgcn_s_setprio(0);

      float t0[8];
      #pragma unroll
      for (int r = 0; r < 8; r++) t0[r] = fmaxf(sacc[r], sacc[r + 8]);
      #pragma unroll
      for (int d = 4; d > 0; d >>= 1)
        #pragma unroll
        for (int r = 0; r < 4; r++) if (r < d) t0[r] = fmaxf(t0[r], t0[r + d]);
      float mx = t0[0];
      i32x2 mm = __builtin_amdgcn_permlane32_swap(__float_as_int(mx), __float_as_int(mx),
                                                  false, false);
      mx = fmaxf(__int_as_float(mm.x), __int_as_float(mm.y));

      if (__any(mx > m + 11.5416f)) {
        float mn = fmaxf(m, mx);
        float al = exp2r(m - mn);
        m = mn; l *= al;
        #pragma unroll
        for (int g = 0; g < 4; g++)
          #pragma unroll
          for (int r = 0; r < 16; r++) oacc[g][r] *= al;
      }

      const int rel = qrow - kt * 64 - v * 32;
      const bool maskT = (kt * 64 + v * 32 + 31) > (q0 + s * 32);
      #pragma unroll
      for (int r = 0; r < 16; r++) {
        float e = exp2r(sacc[r] - m);
        if (maskT) {
          int kl = (r & 3) + 8 * (r >> 2) + 4 * hi;
          e = (kl > rel) ? 0.f : e;
        }
        sacc[r] = e;
      }

      float s0[8];
      #pragma unroll
      for (int r = 0; r < 8; r++) s0[r] = sacc[r] + sacc[r + 8];
      #pragma unroll
      for (int d = 4; d > 0; d >>= 1)
        #pragma unroll
        for (int r = 0; r < 4; r++) if (r < d) s0[r] = s0[r] + s0[r + d];
      l += s0[0];

      bf16x8 pa[2];
      #pragma unroll
      for (int sg = 0; sg < 2; sg++) {
        int q0a = cvtpk(sacc[8 * sg + 0], sacc[8 * sg + 1]);
        int q1a = cvtpk(sacc[8 * sg + 2], sacc[8 * sg + 3]);
        int q0b = cvtpk(sacc[8 * sg + 4], sacc[8 * sg + 5]);
        int q1b = cvtpk(sacc[8 * sg + 6], sacc[8 * sg + 7]);
        i32x2 r0 = __builtin_amdgcn_permlane32_swap(q0a, q0b, false, false);
        i32x2 r1 = __builtin_amdgcn_permlane32_swap(q1a, q1b, false, false);
        union { int d[4]; bf16x8 vv; } u;
        u.d[0] = r0.x; u.d[1] = r1.x; u.d[2] = r0.y; u.d[3] = r1.y;
        pa[sg] = u.vv;
      }

      __builtin_amdgcn_s_setprio(1);
      #pragma unroll
      for (int ks = 0; ks < 2; ks++)
        #pragma unroll
        for (int g = 0; g < 4; g++) {
          int d = g * 32 + c31;
          int row = d >> 1;
          int x = (d & 1) * 128 + v * 64 + ks * 32 + hi * 16;
          bf16x8 vf = *(const bf16x8*)(VsB + row * 256 + (x ^ ((row & 15) << 4)));
          oacc[g] = __builtin_amdgcn_mfma_f32_32x32x16_bf16(vf, pa[ks], oacc[g], 0, 0, 0);
        }
      __builtin_amdgcn_s_setprio(0);
    }
    __syncthreads();
  }

  i32x2 lr = __builtin_amdgcn_permlane32_swap(__float_as_int(l), __float_as_int(l),
                                              false, false);
  l = __int_as_float(lr.x) + __int_as_float(lr.y);

  #pragma unroll
  for (int round = 0; round < 2; round++) {
    const int reg = s & 1;
    const bool active = (s >> 1) == round;
    if (active && v == 1) {
      float* Op = (float*)(LB + reg * 16384);
      #pragma unroll
      for (int g = 0; g < 4; g++)
        #pragma unroll
        for (int rr = 0; rr < 16; rr++) {
          int d = g * 32 + (rr & 3) + 8 * (rr >> 2) + 4 * hi;
          Op[d * 32 + c31] = oacc[g][rr];
        }
      if (hi == 0) {
        float* mm2 = (float*)(LB + 32768 + reg * 256) + c31 * 2;
        mm2[0] = m; mm2[1] = l;
      }
    }
    __syncthreads();
    if (active && v == 0) {
      const float* mm2 = (const float*)(LB + 32768 + reg * 256) + c31 * 2;
      float lB = mm2[1];
      float mB = (lB > 0.f) ? mm2[0] : -3.0e38f;
      float ms = fmaxf(m, mB);
      float aA = exp2r(m - ms), aB = exp2r(mB - ms);
      float linv = 1.0f / (l * aA + lB * aB);
      float sA = aA * linv, sB = aB * linv;
      const float* Op = (const float*)(LB + reg * 16384);
      #pragma unroll
      for (int g = 0; g < 4; g++)
        #pragma unroll
        for (int tt = 0; tt < 4; tt++) {
          float o[4];
          #pragma unroll
          for (int e = 0; e < 4; e++) {
            int d = g * 32 + e + 8 * tt + 4 * hi;
            o[e] = oacc[g][4 * tt + e] * sA + Op[d * 32 + c31] * sB;
          }
          u32x2 pk;
          pk.x = (unsigned)cvtpk(o[0], o[1]);
          pk.y = (unsigned)cvtpk(o[2], o[3]);
          *(u32x2*)(O + (size_t)qrow * DM + h * HD + g * 32 + tt * 8 + hi * 4) = pk;
        }
    }
    __syncthreads();
  }
}

extern "C" void kernel_launch(void* const* d_in, const int* in_sizes, int n_in,
                              void* d_out, int out_size, void* d_ws, size_t ws_size,
                              hipStream_t stream) {
  const float* x  = (const float*)d_in[0];
  const float* wq = (const float*)d_in[1];
  const float* wk = (const float*)d_in[2];
  const float* wv = (const float*)d_in[3];
  const float* wo = (const float*)d_in[4];
  float* out = (float*)d_out;

  const size_t SQDMs = (size_t)SEQ * DM;   // 8M elements
  short* Qb   = (short*)d_ws;
  short* Kb   = Qb + SQDMs;
  short* VTb  = Kb + SQDMs;
  short* Cb   = VTb + SQDMs;
  short* xbf  = Cb + SQDMs;
  short* wbuf = xbf + SQDMs;

  const bool fused = ws_size >= (size_t)107 * 1024 * 1024;
  float2* tab = (float2*)(wbuf + (fused ? (size_t)3 * DM * DM : (size_t)DM * DM));

  rope_tables_kernel<<<SEQ * 64 / 256, 256, 0, stream>>>(tab);
  f32_to_bf16_kernel<<<2048, 256, 0, stream>>>(x, xbf, (int)(SQDMs / 4));

  if (fused) {
    w3_to_bf16_kernel<<<2048, 256, 0, stream>>>(wq, wk, wv, wbuf);
    gemm_qkv12_kernel<<<dim3(SEQ / 256, 32), 768, 0, stream>>>(
        xbf, wbuf, Qb, Kb, VTb);
    rope_apply_kernel<<<SEQ * NH * 16 / 256, 256, 0, stream>>>(Qb, Kb, tab);
  } else {
    f32_to_bf16_kernel<<<2048, 256, 0, stream>>>(wq, wbuf, DM * DM / 4);
    gemm_qkv_kernel<<<dim3(SEQ / 256, 16), 512, 0, stream>>>(
        xbf, wbuf, Qb, Kb, VTb, tab, 0);
    f32_to_bf16_kernel<<<2048, 256, 0, stream>>>(wk, wbuf, DM * DM / 4);
    gemm_qkv_kernel<<<dim3(SEQ / 256, 16), 512, 0, stream>>>(
        xbf, wbuf, Qb, Kb, VTb, tab, 1);
    f32_to_bf16_kernel<<<2048, 256, 0, stream>>>(wv, wbuf, DM * DM / 4);
    gemm_qkv_kernel<<<dim3(SEQ / 256, 16), 512, 0, stream>>>(
        xbf, wbuf, Qb, Kb, VTb, tab, 2);
  }

  flash_attn9_kernel<<<512, 512, 0, stream>>>(Qb, Kb, VTb, Cb);

  f32_to_bf16_kernel<<<2048, 256, 0, stream>>>(wo, wbuf, DM * DM / 4);
  gemm_out_kernel<<<dim3(SEQ / 256, DM / 128), 512, 0, stream>>>(Cb, wbuf, out);
}

// Round 20
// 272.379 us; speedup vs baseline: 1.0686x; 1.0686x over previous
//
#include <hip/hip_runtime.h>
#include <hip/hip_bf16.h>
#include <stdint.h>

#define SEQ 4096
#define DM 2048
#define NH 16
#define HD 128

typedef __attribute__((ext_vector_type(4)))  float f32x4;
typedef __attribute__((ext_vector_type(16))) float f32x16;
typedef __attribute__((ext_vector_type(8)))  short bf16x8;
typedef __attribute__((ext_vector_type(4)))  float float4_t;
typedef __attribute__((ext_vector_type(4)))  short s16x4;
typedef __attribute__((ext_vector_type(2)))  int   i32x2;
typedef __attribute__((ext_vector_type(2)))  unsigned u32x2;

__device__ __forceinline__ short f2bf(float f) {
  union { float f; unsigned u; } c; c.f = f;
  unsigned u = c.u;
  u += 0x7FFFu + ((u >> 16) & 1u);   // RNE
  return (short)(u >> 16);
}

__device__ __forceinline__ int cvtpk(float lo, float hi) {
  int r;
  asm("v_cvt_pk_bf16_f32 %0, %1, %2" : "=v"(r) : "v"(lo), "v"(hi));
  return r;
}

__device__ __forceinline__ float exp2r(float x) {   // raw v_exp_f32
  return __builtin_amdgcn_exp2f(x);
}

__device__ __forceinline__ void async16(const void* g, void* l) {
  __builtin_amdgcn_global_load_lds((const __attribute__((address_space(1))) void*)g,
                                   (__attribute__((address_space(3))) void*)l, 16, 0, 0);
}

__global__ __launch_bounds__(256) void rope_tables_kernel(float2* __restrict__ tab) {
  int idx = blockIdx.x * 256 + threadIdx.x;  // SEQ*64
  int s = idx >> 6, j = idx & 63;
  float invf = expf(-(float)j * (9.210340371976184f / 64.0f)); // 10000^(-j/64)
  float ang = (float)s * invf;
  tab[idx] = make_float2(cosf(ang), sinf(ang));
}

__global__ __launch_bounds__(256) void f32_to_bf16_kernel(const float* __restrict__ in,
                                                          short* __restrict__ out, int n4) {
  int stride = gridDim.x * 256;
  for (int i = blockIdx.x * 256 + threadIdx.x; i < n4; i += stride) {
    float4_t v = ((const float4_t*)in)[i];
    s16x4 r;
    #pragma unroll
    for (int u = 0; u < 4; u++) r[u] = f2bf(v[u]);
    ((s16x4*)out)[i] = r;
  }
}

// Convert 3 weights (wq,wk,wv) into one contiguous bf16 buffer in one launch.
__global__ __launch_bounds__(256) void w3_to_bf16_kernel(
    const float* __restrict__ wq, const float* __restrict__ wk,
    const float* __restrict__ wv, short* __restrict__ out) {
  const int n4w = DM * DM / 4;              // 2^20 per weight
  int stride = gridDim.x * 256;
  for (int i = blockIdx.x * 256 + threadIdx.x; i < 3 * n4w; i += stride) {
    int j = i >> 20;                        // weight index
    int loc = i & (n4w - 1);
    const float* src = (j == 0) ? wq : (j == 1) ? wk : wv;
    float4_t v = ((const float4_t*)src)[loc];
    s16x4 r;
    #pragma unroll
    for (int u = 0; u < 4; u++) r[u] = f2bf(v[u]);
    ((s16x4*)out)[i] = r;
  }
}

// ---------------- fused QKV GEMM, 1-barrier pipeline: BM=256 BN=128 BK=64 --
// One barrier per K-tile; 3-deep bufs (stage target = tile kt-1's buffer,
// protected by the end-of-iteration lgkmcnt(0)+barrier); counted vmcnt(6)
// (tile kt+1 landed, 6 newest loads stay in flight); stage issued mid-body
// (measured best, r17 vs r18); sched_barrier(0) pins MFMAs above the raw
// s_barrier (rule 18). T2 swizzle col ^= (row&7)<<4 on 128B rows.
// B = [6144][2048] concat (wq;wk;wv). Region ry = blockIdx.y>>4 (fused) or
// explicit: 0 -> RoPE+scale into Qout (scale log2e/sqrt(HD), exp2 domain);
// 1 -> RoPE into Kout; 2 -> transposed VTout [N][M].
__global__ __launch_bounds__(512) void gemm_qkv_kernel(
    const short* __restrict__ A, const short* __restrict__ B,
    short* __restrict__ Qout, short* __restrict__ Kout, short* __restrict__ VTout,
    const float2* __restrict__ tab, int region) {
  constexpr int NN = DM, K = DM, MM = SEQ;
  __shared__ __align__(16) char LB[147456];
  const int t = threadIdx.x, lane = t & 63, w = t >> 6;
  const int wm = w >> 1, wn = w & 1;
  const size_t Mbase = (size_t)blockIdx.x * 256;
  const int ry  = (region < 0) ? (blockIdx.y >> 4) : region;
  const int nyl = (region < 0) ? (blockIdx.y & 15) : blockIdx.y;
  const size_t Bbase = (size_t)blockIdx.y * 128;   // row into B buffer
  const size_t Nbase = (size_t)nyl * 128;          // col in 2048-wide output
  const int nt = K / 64;

  auto stageA = [&](int kt, int half) {
    const int buf = kt % 3, k0 = kt * 64;
    #pragma unroll
    for (int it = 0; it < 2; it++) {
      const int ob = half * 16384 + it * 8192 + w * 1024;
      const int o = ob + lane * 16;
      const int row = o >> 7;
      const int col = (o & 127) ^ ((row & 7) << 4);
      async16((const char*)A + ((Mbase + row) * (size_t)K + k0) * 2 + col,
              LB + buf * 32768 + ob);
    }
  };
  auto stageB = [&](int kt) {
    const int buf = kt % 3, k0 = kt * 64;
    #pragma unroll
    for (int it = 0; it < 2; it++) {
      const int ob = it * 8192 + w * 1024;
      const int o = ob + lane * 16;
      const int row = o >> 7;
      const int col = (o & 127) ^ ((row & 7) << 4);
      async16((const char*)B + ((Bbase + row) * (size_t)K + k0) * 2 + col,
              LB + 98304 + buf * 16384 + ob);
    }
  };

  f32x4 acc[4][4] = {};

  stageA(0, 0); stageA(0, 1); stageB(0);
  stageA(1, 0); stageA(1, 1); stageB(1);
  asm volatile("s_waitcnt vmcnt(6)" ::: "memory");   // tile 0 landed
  __builtin_amdgcn_s_barrier();

  for (int kt = 0; kt < nt; kt++) {
    const char* AsB = LB + (kt % 3) * 32768;
    const char* BsB = LB + 98304 + (kt % 3) * 16384;
    const bool pre = (kt + 2 < nt);
    bf16x8 a[2][4], b[2][2], b2[2][2];

    #pragma unroll
    for (int ks = 0; ks < 2; ks++)
      #pragma unroll
      for (int m = 0; m < 4; m++) {
        int row = wm * 64 + m * 16 + (lane & 15);
        a[ks][m] = *(const bf16x8*)(AsB + row * 128
                    + ((ks * 64 + (lane >> 4) * 16) ^ ((row & 7) << 4)));
      }
    #pragma unroll
    for (int ks = 0; ks < 2; ks++)
      #pragma unroll
      for (int n = 0; n < 2; n++) {
        int row = n * 32 + wn * 16 + (lane & 15);
        b[ks][n] = *(const bf16x8*)(BsB + row * 128
                    + ((ks * 64 + (lane >> 4) * 16) ^ ((row & 7) << 4)));
      }
    if (pre) { stageA(kt + 2, 0); stageA(kt + 2, 1); stageB(kt + 2); }

    __builtin_amdgcn_s_setprio(1);
    #pragma unroll
    for (int ks = 0; ks < 2; ks++)
      #pragma unroll
      for (int m = 0; m < 4; m++)
        #pragma unroll
        for (int n = 0; n < 2; n++)
          acc[m][n] = __builtin_amdgcn_mfma_f32_16x16x32_bf16(
              a[ks][m], b[ks][n], acc[m][n], 0, 0, 0);
    __builtin_amdgcn_s_setprio(0);

    #pragma unroll
    for (int ks = 0; ks < 2; ks++)
      #pragma unroll
      for (int n = 0; n < 2; n++) {
        int row = (n + 2) * 32 + wn * 16 + (lane & 15);
        b2[ks][n] = *(const bf16x8*)(BsB + row * 128
                     + ((ks * 64 + (lane >> 4) * 16) ^ ((row & 7) << 4)));
      }
    __builtin_amdgcn_s_setprio(1);
    #pragma unroll
    for (int ks = 0; ks < 2; ks++)
      #pragma unroll
      for (int m = 0; m < 4; m++)
        #pragma unroll
        for (int n = 0; n < 2; n++)
          acc[m][n + 2] = __builtin_amdgcn_mfma_f32_16x16x32_bf16(
              a[ks][m], b2[ks][n], acc[m][n + 2], 0, 0, 0);
    __builtin_amdgcn_s_setprio(0);

    if (kt + 1 < nt) {
      if (pre) asm volatile("s_waitcnt vmcnt(6) lgkmcnt(0)" ::: "memory");
      else     asm volatile("s_waitcnt vmcnt(0) lgkmcnt(0)" ::: "memory");
      __builtin_amdgcn_sched_barrier(0);
      __builtin_amdgcn_s_barrier();
    }
  }

  if (ry < 2) {
    const float SC = (ry == 0) ? 0.12751746f : 1.0f;  // log2e/sqrt(128) | 1
    short* C = (ry == 0) ? Qout : Kout;
    #pragma unroll
    for (int m = 0; m < 4; m++)
      #pragma unroll
      for (int n = 0; n < 2; n++)
        #pragma unroll
        for (int j = 0; j < 4; j++) {
          int row = (int)Mbase + wm * 64 + m * 16 + (lane >> 4) * 4 + j;  // seq
          int dj = n * 32 + wn * 16 + (lane & 15);                        // 0..63
          float2 cs = tab[row * 64 + dj];
          float cc = cs.x * SC, ss = cs.y * SC;
          float r1 = acc[m][n][j], r2 = acc[m][n + 2][j];
          C[(size_t)row * NN + Nbase + dj]      = f2bf(r1 * cc - r2 * ss);
          C[(size_t)row * NN + Nbase + dj + 64] = f2bf(r2 * cc + r1 * ss);
        }
  } else {
    #pragma unroll
    for (int m = 0; m < 4; m++)
      #pragma unroll
      for (int n = 0; n < 4; n++)
        #pragma unroll
        for (int j = 0; j < 4; j++) {
          size_t row = Mbase + wm * 64 + m * 16 + (lane >> 4) * 4 + j;
          size_t col = Nbase + n * 32 + wn * 16 + (lane & 15);
          VTout[col * (size_t)MM + row] = f2bf(acc[m][n][j]);
        }
  }
}

// ---------------- out-projection GEMM, same pipeline (f32 C) ---------------
__global__ __launch_bounds__(512) void gemm_out_kernel(
    const short* __restrict__ A, const short* __restrict__ B,
    float* __restrict__ Cp) {
  constexpr int NN = DM, K = DM;
  __shared__ __align__(16) char LB[147456];
  const int t = threadIdx.x, lane = t & 63, w = t >> 6;
  const int wm = w >> 1, wn = w & 1;
  const size_t Mbase = (size_t)blockIdx.x * 256;
  const size_t Nbase = (size_t)blockIdx.y * 128;
  const int nt = K / 64;

  auto stageA = [&](int kt, int half) {
    const int buf = kt % 3, k0 = kt * 64;
    #pragma unroll
    for (int it = 0; it < 2; it++) {
      const int ob = half * 16384 + it * 8192 + w * 1024;
      const int o = ob + lane * 16;
      const int row = o >> 7;
      const int col = (o & 127) ^ ((row & 7) << 4);
      async16((const char*)A + ((Mbase + row) * (size_t)K + k0) * 2 + col,
              LB + buf * 32768 + ob);
    }
  };
  auto stageB = [&](int kt) {
    const int buf = kt % 3, k0 = kt * 64;
    #pragma unroll
    for (int it = 0; it < 2; it++) {
      const int ob = it * 8192 + w * 1024;
      const int o = ob + lane * 16;
      const int row = o >> 7;
      const int col = (o & 127) ^ ((row & 7) << 4);
      async16((const char*)B + ((Nbase + row) * (size_t)K + k0) * 2 + col,
              LB + 98304 + buf * 16384 + ob);
    }
  };

  f32x4 acc[4][4] = {};

  stageA(0, 0); stageA(0, 1); stageB(0);
  stageA(1, 0); stageA(1, 1); stageB(1);
  asm volatile("s_waitcnt vmcnt(6)" ::: "memory");
  __builtin_amdgcn_s_barrier();

  for (int kt = 0; kt < nt; kt++) {
    const char* AsB = LB + (kt % 3) * 32768;
    const char* BsB = LB + 98304 + (kt % 3) * 16384;
    const bool pre = (kt + 2 < nt);
    bf16x8 a[2][4], b[2][2], b2[2][2];

    #pragma unroll
    for (int ks = 0; ks < 2; ks++)
      #pragma unroll
      for (int m = 0; m < 4; m++) {
        int row = wm * 64 + m * 16 + (lane & 15);
        a[ks][m] = *(const bf16x8*)(AsB + row * 128
                    + ((ks * 64 + (lane >> 4) * 16) ^ ((row & 7) << 4)));
      }
    #pragma unroll
    for (int ks = 0; ks < 2; ks++)
      #pragma unroll
      for (int n = 0; n < 2; n++) {
        int row = n * 32 + wn * 16 + (lane & 15);
        b[ks][n] = *(const bf16x8*)(BsB + row * 128
                    + ((ks * 64 + (lane >> 4) * 16) ^ ((row & 7) << 4)));
      }
    if (pre) { stageA(kt + 2, 0); stageA(kt + 2, 1); stageB(kt + 2); }

    __builtin_amdgcn_s_setprio(1);
    #pragma unroll
    for (int ks = 0; ks < 2; ks++)
      #pragma unroll
      for (int m = 0; m < 4; m++)
        #pragma unroll
        for (int n = 0; n < 2; n++)
          acc[m][n] = __builtin_amdgcn_mfma_f32_16x16x32_bf16(
              a[ks][m], b[ks][n], acc[m][n], 0, 0, 0);
    __builtin_amdgcn_s_setprio(0);

    #pragma unroll
    for (int ks = 0; ks < 2; ks++)
      #pragma unroll
      for (int n = 0; n < 2; n++) {
        int row = (n + 2) * 32 + wn * 16 + (lane & 15);
        b2[ks][n] = *(const bf16x8*)(BsB + row * 128
                     + ((ks * 64 + (lane >> 4) * 16) ^ ((row & 7) << 4)));
      }
    __builtin_amdgcn_s_setprio(1);
    #pragma unroll
    for (int ks = 0; ks < 2; ks++)
      #pragma unroll
      for (int m = 0; m < 4; m++)
        #pragma unroll
        for (int n = 0; n < 2; n++)
          acc[m][n + 2] = __builtin_amdgcn_mfma_f32_16x16x32_bf16(
              a[ks][m], b2[ks][n], acc[m][n + 2], 0, 0, 0);
    __builtin_amdgcn_s_setprio(0);

    if (kt + 1 < nt) {
      if (pre) asm volatile("s_waitcnt vmcnt(6) lgkmcnt(0)" ::: "memory");
      else     asm volatile("s_waitcnt vmcnt(0) lgkmcnt(0)" ::: "memory");
      __builtin_amdgcn_sched_barrier(0);
      __builtin_amdgcn_s_barrier();
    }
  }

  #pragma unroll
  for (int m = 0; m < 4; m++)
    #pragma unroll
    for (int n = 0; n < 4; n++)
      #pragma unroll
      for (int j = 0; j < 4; j++) {
        size_t row = Mbase + wm * 64 + m * 16 + (lane >> 4) * 4 + j;
        size_t col = Nbase + n * 32 + wn * 16 + (lane & 15);
        Cp[row * NN + col] = acc[m][n][j];
      }
}

// ---------------- flash attention (best measured: ~107-108 us) -------------
// 512 thr, 8 waves = 4 q-strips (32 rows) x 2 kv-halves (32 keys), KVBLK=64,
// QBLK=128. Grid 512 = 16 heads x 32 q-tiles; (qt=pr, 31-pr) at b, b+256.
// LDS exactly 64KB; packed V^T (2 d-rows per 256B row, XOR (row&15)<<4 =
// 2-way free). Q pre-scaled by log2e/sqrt(HD) (exp2 domain); VT is [DM][SEQ].
// S^T = mfma(K,Q) -> in-lane softmax; O^T = mfma(VT,P^T);
// T12 cvt_pk+permlane32_swap; T13 defer-max (THR=8/ln2); LDS merge of halves.
__global__ __launch_bounds__(512) void flash_attn9_kernel(
    const short* __restrict__ Q, const short* __restrict__ K,
    const short* __restrict__ VT, short* __restrict__ O) {
  __shared__ __align__(16) char LB[65536];
  const int t = threadIdx.x, lane = t & 63, w = t >> 6;   // w: 0..7
  const int hi = lane >> 5, c31 = lane & 31;
  const int s = w & 3, v = w >> 2;                // strip, kv-half
  const int id = blockIdx.x;                      // 0..511
  const int h  = (id & 7) * 2 + ((id >> 3) & 1);  // 2 heads per XCD
  const int pr = (id >> 4) & 15;                  // 0..15
  const int qt = (id < 256) ? pr : (31 - pr);     // 128-row q-tile

  auto stage = [&](int kt, int buf) {
    #pragma unroll
    for (int it = 0; it < 2; it++) {
      const int ob = it * 8192 + w * 1024;        // wave-uniform LDS byte base
      const int o  = ob + lane * 16;
      const int row = o >> 8;                     // 0..63
      const int xs = (o & 255) ^ ((row & 15) << 4);
      { const size_t src = ((size_t)(kt * 64 + row) * DM + h * HD) * 2 + xs;
        async16((const char*)K + src, LB + buf * 16384 + ob); }
      { const int d = 2 * row + (xs >> 7);
        const size_t src = ((size_t)(h * HD + d) * SEQ + (size_t)kt * 64) * 2
                         + (size_t)(xs & 127);
        async16((const char*)VT + src, LB + 32768 + buf * 16384 + ob); }
    }
  };

  const int q0 = qt * 128;
  const int nt = 2 * (qt + 1);                    // 64-key tiles
  const int qrow = q0 + s * 32 + c31;             // this lane's q-row

  stage(0, 0);

  bf16x8 qf[8];
  #pragma unroll
  for (int ss = 0; ss < 8; ss++)
    qf[ss] = *(const bf16x8*)(Q + (size_t)qrow * DM + h * HD + ss * 16 + hi * 8);

  f32x16 oacc[4] = {};
  float m = -3.0e38f, l = 0.f;

  __syncthreads();                                // stage(0) landed

  for (int kt = 0; kt < nt; kt++) {
    const int buf = kt & 1;
    if (kt + 1 < nt) stage(kt + 1, buf ^ 1);

    if (kt * 64 + v * 32 <= q0 + s * 32 + 31) {   // wave has unmasked work
      const char* KsB = LB + buf * 16384;
      const char* VsB = LB + 32768 + buf * 16384;

      f32x16 sacc = {};
      __builtin_amdgcn_s_setprio(1);
      #pragma unroll
      for (int ss = 0; ss < 8; ss++) {
        int row = v * 32 + c31;
        bf16x8 kf = *(const bf16x8*)(KsB + row * 256
                                     + ((ss * 32 + hi * 16) ^ ((row & 15) << 4)));
        sacc = __builtin_amdgcn_mfma_f32_32x32x16_bf16(kf, qf[ss], sacc, 0, 0, 0);
      }
      __builtin_amdgcn_s_setprio(0);

      float t0[8];
      #pragma unroll
      for (int r = 0; r < 8; r++) t0[r] = fmaxf(sacc[r], sacc[r + 8]);
      #pragma unroll
      for (int d = 4; d > 0; d >>= 1)
        #pragma unroll
        for (int r = 0; r < 4; r++) if (r < d) t0[r] = fmaxf(t0[r], t0[r + d]);
      float mx = t0[0];
      i32x2 mm = __builtin_amdgcn_permlane32_swap(__float_as_int(mx), __float_as_int(mx),
                                                  false, false);
      mx = fmaxf(__int_as_float(mm.x), __int_as_float(mm.y));

      if (__any(mx > m + 11.5416f)) {
        float mn = fmaxf(m, mx);
        float al = exp2r(m - mn);
        m = mn; l *= al;
        #pragma unroll
        for (int g = 0; g < 4; g++)
          #pragma unroll
          for (int r = 0; r < 16; r++) oacc[g][r] *= al;
      }

      const int rel = qrow - kt * 64 - v * 32;
      const bool maskT = (kt * 64 + v * 32 + 31) > (q0 + s * 32);
      #pragma unroll
      for (int r = 0; r < 16; r++) {
        float e = exp2r(sacc[r] - m);
        if (maskT) {
          int kl = (r & 3) + 8 * (r >> 2) + 4 * hi;
          e = (kl > rel) ? 0.f : e;
        }
        sacc[r] = e;
      }

      float s0[8];
      #pragma unroll
      for (int r = 0; r < 8; r++) s0[r] = sacc[r] + sacc[r + 8];
      #pragma unroll
      for (int d = 4; d > 0; d >>= 1)
        #pragma unroll
        for (int r = 0; r < 4; r++) if (r < d) s0[r] = s0[r] + s0[r + d];
      l += s0[0];

      bf16x8 pa[2];
      #pragma unroll
      for (int sg = 0; sg < 2; sg++) {
        int q0a = cvtpk(sacc[8 * sg + 0], sacc[8 * sg + 1]);
        int q1a = cvtpk(sacc[8 * sg + 2], sacc[8 * sg + 3]);
        int q0b = cvtpk(sacc[8 * sg + 4], sacc[8 * sg + 5]);
        int q1b = cvtpk(sacc[8 * sg + 6], sacc[8 * sg + 7]);
        i32x2 r0 = __builtin_amdgcn_permlane32_swap(q0a, q0b, false, false);
        i32x2 r1 = __builtin_amdgcn_permlane32_swap(q1a, q1b, false, false);
        union { int d[4]; bf16x8 vv; } u;
        u.d[0] = r0.x; u.d[1] = r1.x; u.d[2] = r0.y; u.d[3] = r1.y;
        pa[sg] = u.vv;
      }

      __builtin_amdgcn_s_setprio(1);
      #pragma unroll
      for (int ks = 0; ks < 2; ks++)
        #pragma unroll
        for (int g = 0; g < 4; g++) {
          int d = g * 32 + c31;
          int row = d >> 1;
          int x = (d & 1) * 128 + v * 64 + ks * 32 + hi * 16;
          bf16x8 vf = *(const bf16x8*)(VsB + row * 256 + (x ^ ((row & 15) << 4)));
          oacc[g] = __builtin_amdgcn_mfma_f32_32x32x16_bf16(vf, pa[ks], oacc[g], 0, 0, 0);
        }
      __builtin_amdgcn_s_setprio(0);
    }
    __syncthreads();
  }

  i32x2 lr = __builtin_amdgcn_permlane32_swap(__float_as_int(l), __float_as_int(l),
                                              false, false);
  l = __int_as_float(lr.x) + __int_as_float(lr.y);

  #pragma unroll
  for (int round = 0; round < 2; round++) {
    const int reg = s & 1;
    const bool active = (s >> 1) == round;
    if (active && v == 1) {
      float* Op = (float*)(LB + reg * 16384);
      #pragma unroll
      for (int g = 0; g < 4; g++)
        #pragma unroll
        for (int rr = 0; rr < 16; rr++) {
          int d = g * 32 + (rr & 3) + 8 * (rr >> 2) + 4 * hi;
          Op[d * 32 + c31] = oacc[g][rr];
        }
      if (hi == 0) {
        float* mm2 = (float*)(LB + 32768 + reg * 256) + c31 * 2;
        mm2[0] = m; mm2[1] = l;
      }
    }
    __syncthreads();
    if (active && v == 0) {
      const float* mm2 = (const float*)(LB + 32768 + reg * 256) + c31 * 2;
      float lB = mm2[1];
      float mB = (lB > 0.f) ? mm2[0] : -3.0e38f;
      float ms = fmaxf(m, mB);
      float aA = exp2r(m - ms), aB = exp2r(mB - ms);
      float linv = 1.0f / (l * aA + lB * aB);
      float sA = aA * linv, sB = aB * linv;
      const float* Op = (const float*)(LB + reg * 16384);
      #pragma unroll
      for (int g = 0; g < 4; g++)
        #pragma unroll
        for (int tt = 0; tt < 4; tt++) {
          float o[4];
          #pragma unroll
          for (int e = 0; e < 4; e++) {
            int d = g * 32 + e + 8 * tt + 4 * hi;
            o[e] = oacc[g][4 * tt + e] * sA + Op[d * 32 + c31] * sB;
          }
          u32x2 pk;
          pk.x = (unsigned)cvtpk(o[0], o[1]);
          pk.y = (unsigned)cvtpk(o[2], o[3]);
          *(u32x2*)(O + (size_t)qrow * DM + h * HD + g * 32 + tt * 8 + hi * 4) = pk;
        }
    }
    __syncthreads();
  }
}

extern "C" void kernel_launch(void* const* d_in, const int* in_sizes, int n_in,
                              void* d_out, int out_size, void* d_ws, size_t ws_size,
                              hipStream_t stream) {
  const float* x  = (const float*)d_in[0];
  const float* wq = (const float*)d_in[1];
  const float* wk = (const float*)d_in[2];
  const float* wv = (const float*)d_in[3];
  const float* wo = (const float*)d_in[4];
  float* out = (float*)d_out;

  const size_t SQDMs = (size_t)SEQ * DM;   // 8M elements
  short* Qb   = (short*)d_ws;
  short* Kb   = Qb + SQDMs;
  short* VTb  = Kb + SQDMs;
  short* Cb   = VTb + SQDMs;
  short* xbf  = Cb + SQDMs;
  short* wbuf = xbf + SQDMs;

  const bool fused = ws_size >= (size_t)107 * 1024 * 1024;
  float2* tab = (float2*)(wbuf + (fused ? (size_t)3 * DM * DM : (size_t)DM * DM));

  rope_tables_kernel<<<SEQ * 64 / 256, 256, 0, stream>>>(tab);
  f32_to_bf16_kernel<<<2048, 256, 0, stream>>>(x, xbf, (int)(SQDMs / 4));

  if (fused) {
    w3_to_bf16_kernel<<<2048, 256, 0, stream>>>(wq, wk, wv, wbuf);
    gemm_qkv_kernel<<<dim3(SEQ / 256, 48), 512, 0, stream>>>(
        xbf, wbuf, Qb, Kb, VTb, tab, -1);
  } else {
    f32_to_bf16_kernel<<<2048, 256, 0, stream>>>(wq, wbuf, DM * DM / 4);
    gemm_qkv_kernel<<<dim3(SEQ / 256, 16), 512, 0, stream>>>(
        xbf, wbuf, Qb, Kb, VTb, tab, 0);
    f32_to_bf16_kernel<<<2048, 256, 0, stream>>>(wk, wbuf, DM * DM / 4);
    gemm_qkv_kernel<<<dim3(SEQ / 256, 16), 512, 0, stream>>>(
        xbf, wbuf, Qb, Kb, VTb, tab, 1);
    f32_to_bf16_kernel<<<2048, 256, 0, stream>>>(wv, wbuf, DM * DM / 4);
    gemm_qkv_kernel<<<dim3(SEQ / 256, 16), 512, 0, stream>>>(
        xbf, wbuf, Qb, Kb, VTb, tab, 2);
  }

  flash_attn9_kernel<<<512, 512, 0, stream>>>(Qb, Kb, VTb, Cb);

  f32_to_bf16_kernel<<<2048, 256, 0, stream>>>(wo, wbuf, DM * DM / 4);
  gemm_out_kernel<<<dim3(SEQ / 256, DM / 128), 512, 0, stream>>>(Cb, wbuf, out);
}